// Round 1
// baseline (46.985 us; speedup 1.0000x reference)
//
#include <hip/hip_runtime.h>

// out[b,s,d] = x[b,s,d] + pe[d], D=1024, pe[2j]=sin(10000^(2j/D)), pe[2j+1]=cos(...)
// x: (8, 4096, 1024) fp32 = 33,554,432 elems. Memory-bound streaming add.
//
// block=256 threads, each thread handles one float4 column (4 elems) of the
// 1024-wide row; grid-stride is a multiple of 256 float4s so the column is
// invariant per thread -> PE computed ONCE per thread in registers.

__global__ void __launch_bounds__(256)
_PositionalEncoding_60395830117137_kernel(const float4* __restrict__ x,
                                          float4* __restrict__ out,
                                          long long n4) {
    const int c = threadIdx.x;  // float4 column within the row: elements 4c..4c+3

    // j indices into denominator array: j = 2c and 2c+1 (each j gives sin/cos pair)
    const float ja = 2.0f * (float)c;
    const float jb = ja + 1.0f;
    // exp = 2*j / 1024 ; den = 10000^exp
    const float den_a = powf(10000.0f, ja * (2.0f / 1024.0f));
    const float den_b = powf(10000.0f, jb * (2.0f / 1024.0f));

    float4 pe;
    pe.x = sinf(den_a);
    pe.y = cosf(den_a);
    pe.z = sinf(den_b);
    pe.w = cosf(den_b);

    long long idx = (long long)blockIdx.x * 256 + c;
    const long long stride = (long long)gridDim.x * 256;  // multiple of 256 -> column fixed
    for (; idx < n4; idx += stride) {
        float4 v = x[idx];
        v.x += pe.x;
        v.y += pe.y;
        v.z += pe.z;
        v.w += pe.w;
        out[idx] = v;
    }
}

extern "C" void kernel_launch(void* const* d_in, const int* in_sizes, int n_in,
                              void* d_out, int out_size, void* d_ws, size_t ws_size,
                              hipStream_t stream) {
    const float* x = (const float*)d_in[0];
    float* out = (float*)d_out;

    const long long n = (long long)in_sizes[0];  // 8*4096*1024 = 33,554,432 (multiple of 4)
    const long long n4 = n / 4;

    const int block = 256;
    const int grid = 2048;  // grid-stride covers the rest; 16 float4s/thread

    _PositionalEncoding_60395830117137_kernel<<<grid, block, 0, stream>>>(
        (const float4*)x, (float4*)out, n4);
}